// Round 5
// baseline (327.638 us; speedup 1.0000x reference)
//
#include <hip/hip_runtime.h>

typedef __attribute__((ext_vector_type(8))) short short8;
typedef __attribute__((ext_vector_type(4))) short short4v;
typedef __attribute__((ext_vector_type(4))) float float4a;
typedef __attribute__((ext_vector_type(16))) float float16a;

#define MFMA16(a, b, c) __builtin_amdgcn_mfma_f32_16x16x32_bf16(a, b, c, 0, 0, 0)
#define MFMA32(a, b, c) __builtin_amdgcn_mfma_f32_32x32x16_bf16(a, b, c, 0, 0, 0)

static __device__ __forceinline__ short f2bf(float f) {
  unsigned u = __builtin_bit_cast(unsigned, f);
  u += 0x7fff + ((u >> 16) & 1);   // RNE
  return (short)(u >> 16);
}
static __device__ __forceinline__ float bf2f(short s) {
  unsigned u = ((unsigned)(unsigned short)s) << 16;
  return __builtin_bit_cast(float, u);
}

// async global->LDS, 16 B per lane. LDS dest must be wave-uniform base + lane*16.
static __device__ __forceinline__ void gl2lds(const short* g, short* l) {
  __builtin_amdgcn_global_load_lds(
      (const __attribute__((address_space(1))) void*)g,
      (__attribute__((address_space(3))) void*)l,
      16, 0, 0);
}

// ---- fused f32->bf16 conversion for all 8 tensors ----
struct Cvt8 { const float* in[8]; short* out[8]; };
__global__ __launch_bounds__(256) void cvt8_k(Cvt8 a) {
  int b = blockIdx.x, seg, rb;
  if (b < 12288)      { seg = b >> 12;                 rb = b & 4095; }
  else if (b < 16384) { seg = 3 + ((b - 12288) >> 10); rb = (b - 12288) & 1023; }
  else                { seg = 7;                       rb = b - 16384; }
  int i = rb * 256 + threadIdx.x;
  float4a v = ((const float4a*)a.in[seg])[i];
  short4v o;
  o.x = f2bf(v.x); o.y = f2bf(v.y); o.z = f2bf(v.z); o.w = f2bf(v.w);
  ((short4v*)a.out[seg])[i] = o;
}

// ---- tiled GEMM: C = A @ W^T, 128x128 tile, BK=32. Fused Q/K/V projections. ----
__global__ __launch_bounds__(256) void gemm_qkv(
    const short* __restrict__ Qb, const short* __restrict__ Kb, const short* __restrict__ Vb,
    const short* __restrict__ Wq, const short* __restrict__ Wk, const short* __restrict__ Wv,
    short* __restrict__ Qp, short* __restrict__ Kp, short* __restrict__ Vt) {
  __shared__ short As[128 * 32];
  __shared__ short Bs[128 * 32];
  int seg = blockIdx.x >> 8, bid = blockIdx.x & 255;
  const short* A = seg == 0 ? Qb : (seg == 1 ? Kb : Vb);
  const short* W = seg == 0 ? Wq : (seg == 1 ? Wk : Wv);
  int mt = bid >> 3, nt = bid & 7;
  int m0 = mt * 128, n0 = nt * 128;
  int lane = threadIdx.x & 63, wid = threadIdx.x >> 6;
  int l15 = lane & 15, quad = lane >> 4;
  int wm = wid & 1, wn = wid >> 1;

  int lrow = lane >> 2, lcol = (lane & 3) * 8;
  const short* gA = A + (m0 + wid * 32 + lrow) * 1024 + lcol;
  const short* gB = W + (n0 + wid * 32 + lrow) * 1024 + lcol;
  short* lA = As + (wid * 32) * 32 + lane * 8;
  short* lB = Bs + (wid * 32) * 32 + lane * 8;

  float4a acc[4][4];
#pragma unroll
  for (int i = 0; i < 4; ++i)
#pragma unroll
    for (int j = 0; j < 4; ++j) acc[i][j] = (float4a){0, 0, 0, 0};

  for (int kc = 0; kc < 1024; kc += 32) {
    __syncthreads();
    gl2lds(gA + kc, lA);
    gl2lds(gA + 16 * 1024 + kc, lA + 16 * 32);
    gl2lds(gB + kc, lB);
    gl2lds(gB + 16 * 1024 + kc, lB + 16 * 32);
    __syncthreads();
    short8 af[4], bfr[4];
#pragma unroll
    for (int i = 0; i < 4; ++i)
      af[i] = *(const short8*)&As[(wm * 64 + i * 16 + l15) * 32 + quad * 8];
#pragma unroll
    for (int j = 0; j < 4; ++j)
      bfr[j] = *(const short8*)&Bs[(wn * 64 + j * 16 + l15) * 32 + quad * 8];
#pragma unroll
    for (int i = 0; i < 4; ++i)
#pragma unroll
      for (int j = 0; j < 4; ++j) acc[i][j] = MFMA16(af[i], bfr[j], acc[i][j]);
  }

#pragma unroll
  for (int i = 0; i < 4; ++i)
#pragma unroll
    for (int j = 0; j < 4; ++j)
#pragma unroll
      for (int r = 0; r < 4; ++r) {
        int m = m0 + wm * 64 + i * 16 + quad * 4 + r;
        int n = n0 + wn * 64 + j * 16 + l15;
        int bb = m >> 10, s = m & 1023, hh = n >> 7, d = n & 127;
        short v = f2bf(acc[i][j][r]);
        if (seg == 0)      Qp[(((bb * 8 + hh) * 1024) + s) * 128 + d] = v;
        else if (seg == 1) Kp[(((bb * 8 + hh) * 1024) + s) * 128 + d] = v;
        else               Vt[(bb * 8 + hh) * 131072 + d * 1024 + s] = v;
      }
}

// ---- output projection: out(f32) = O2 @ Wo^T. 128x64 tiles -> 512 blocks. ----
__global__ __launch_bounds__(256) void gemm_o(const short* __restrict__ A,
                                              const short* __restrict__ W,
                                              float* __restrict__ C) {
  __shared__ short As[128 * 32];
  __shared__ short Bs[64 * 32];
  int bid = blockIdx.x;
  int mt = bid >> 4, nt = bid & 15;
  int m0 = mt * 128, n0 = nt * 64;
  int lane = threadIdx.x & 63, wid = threadIdx.x >> 6;
  int l15 = lane & 15, quad = lane >> 4;
  int wm = wid & 1, wn = wid >> 1;

  int lrow = lane >> 2, lcol = (lane & 3) * 8;
  const short* gA = A + (m0 + wid * 32 + lrow) * 1024 + lcol;
  const short* gB = W + (n0 + wid * 16 + (lane >> 2)) * 1024 + lcol;
  short* lA = As + (wid * 32) * 32 + lane * 8;
  short* lB = Bs + (wid * 16) * 32 + lane * 8;

  float4a acc[4][2];
#pragma unroll
  for (int i = 0; i < 4; ++i)
#pragma unroll
    for (int j = 0; j < 2; ++j) acc[i][j] = (float4a){0, 0, 0, 0};

  for (int kc = 0; kc < 1024; kc += 32) {
    __syncthreads();
    gl2lds(gA + kc, lA);
    gl2lds(gA + 16 * 1024 + kc, lA + 16 * 32);
    gl2lds(gB + kc, lB);
    __syncthreads();
    short8 af[4], bfr[2];
#pragma unroll
    for (int i = 0; i < 4; ++i)
      af[i] = *(const short8*)&As[(wm * 64 + i * 16 + l15) * 32 + quad * 8];
#pragma unroll
    for (int j = 0; j < 2; ++j)
      bfr[j] = *(const short8*)&Bs[(wn * 32 + j * 16 + l15) * 32 + quad * 8];
#pragma unroll
    for (int i = 0; i < 4; ++i)
#pragma unroll
      for (int j = 0; j < 2; ++j) acc[i][j] = MFMA16(af[i], bfr[j], acc[i][j]);
  }

#pragma unroll
  for (int i = 0; i < 4; ++i)
#pragma unroll
    for (int j = 0; j < 2; ++j)
#pragma unroll
      for (int r = 0; r < 4; ++r) {
        int m = m0 + wm * 64 + i * 16 + quad * 4 + r;
        int n = n0 + wn * 32 + j * 16 + l15;
        C[m * 1024 + n] = acc[i][j][r];
      }
}

// Qrel[bh, q, r] = sum_d Qp[bh,q,d] * rel[h,r,d]   (bf16 out)
__global__ __launch_bounds__(256) void qrel_k(const short* __restrict__ Qp,
                                              const short* __restrict__ rel,
                                              short* __restrict__ Qrel) {
  int lane = threadIdx.x & 63, wid = threadIdx.x >> 6;
  int gw = blockIdx.x * 4 + wid;
  int bh = gw / 1088;
  int rem = gw - bh * 1088;
  int mt = rem / 17;
  int nt = rem - mt * 17;
  int l15 = lane & 15, quad = lane >> 4;
  int h = bh & 7;

  const short* arow = Qp + bh * 131072 + (mt * 16 + l15) * 128 + quad * 8;
  int col = nt * 16 + l15;
  int colc = col > 256 ? 256 : col;
  const short* brow = rel + (h * 257 + colc) * 128 + quad * 8;

  float4a acc = {0, 0, 0, 0};
#pragma unroll
  for (int kc = 0; kc < 128; kc += 32) {
    short8 a = *(const short8*)(arow + kc);
    short8 b = *(const short8*)(brow + kc);
    acc = MFMA16(a, b, acc);
  }
  if (col < 257) {
#pragma unroll
    for (int r = 0; r < 4; ++r) {
      int q = mt * 16 + quad * 4 + r;
      Qrel[bh * 263168 + q * 257 + col] = f2bf(acc[r]);
    }
  }
}

// Banded attention, no-max flash, 32x32x16 MFMA. Block = 2 waves over the same
// 32-query tile; waves take alternating 32-key chunks; LDS combine at the end.
__global__ __launch_bounds__(128) void attn_k(const short* __restrict__ Qp,
                                              const short* __restrict__ Kp,
                                              const short* __restrict__ Vt,
                                              const short* __restrict__ Qrel,
                                              const unsigned char* __restrict__ kpm,
                                              short* __restrict__ O2) {
  __shared__ short plds[2][32][40];    // P tile per wave; stride 40 keeps rows 16B-aligned
  __shared__ float obuf[32][132];      // wave-1 O partial
  __shared__ float lbuf[32];           // wave-1 l partial
  int lane = threadIdx.x & 63, wid = threadIdx.x >> 6;
  int bh = blockIdx.x >> 5, qt = blockIdx.x & 31;
  int q0 = qt * 32;
  int l31 = lane & 31, hl = lane >> 5;
  int b = bh >> 3, h = bh & 7;

  // Q A-fragments: lane holds Q[q0+l31][s*16 + hl*8 + j]
  short8 aq[8];
  const short* qrow = Qp + bh * 131072 + (q0 + l31) * 128 + hl * 8;
#pragma unroll
  for (int s = 0; s < 8; ++s) aq[s] = *(const short8*)(qrow + s * 16);

  float16a O[4];
#pragma unroll
  for (int d = 0; d < 4; ++d)
#pragma unroll
    for (int i = 0; i < 16; ++i) O[d][i] = 0.f;
  float lsum[16];
#pragma unroll
  for (int i = 0; i < 16; ++i) lsum[i] = 0.f;

  int klo = q0 - 256; if (klo < 0) klo = 0; klo &= ~31;
  int khi = q0 + 288; if (khi > 1024) khi = 1024; khi = (khi + 31) & ~31;
  const float sc = 0.08838834764831845f;  // 1/sqrt(128)

  const short* kbase = Kp + bh * 131072 + hl * 8;
  const short* vbase = Vt + bh * 131072 + hl * 8;
  const short* qrbase = Qrel + bh * 263168;
  const unsigned char* pmrow = kpm + b * 1024;

  for (int k0 = klo + wid * 32; k0 < khi; k0 += 64) {
    // QK^T: S[32q][32k]
    const short* krow = kbase + (k0 + l31) * 128;
    float16a S;
#pragma unroll
    for (int i = 0; i < 16; ++i) S[i] = 0.f;
#pragma unroll
    for (int s = 0; s < 8; ++s) {
      short8 kb = *(const short8*)(krow + s * 16);
      S = MFMA32(aq[s], kb, S);
    }
    int key = k0 + l31;            // C-layout: col = lane&31 = key
    int pmv = pmrow[key];
    // exp + P store (C-layout row = (i&3)+8*(i>>2)+4*hl)
#pragma unroll
    for (int i = 0; i < 16; ++i) {
      int qoff = (i & 3) + 8 * (i >> 2) + 4 * hl;
      int q = q0 + qoff;
      int d = key - q;
      int rr = d < -128 ? 0 : (d > 128 ? 256 : d + 128);
      float rel = bf2f(qrbase[q * 257 + rr]);
      int msk = (d < -256) | (d > 256) | pmv;
      float pe = msk ? 0.f : __expf((S[i] + rel) * sc);
      lsum[i] += pe;
      plds[wid][qoff][l31] = f2bf(pe);
    }
    // P A-fragments (m = l31, k = sub*16 + hl*8 + j) and PV
    short8 ap0 = *(const short8*)&plds[wid][l31][hl * 8];
    short8 ap1 = *(const short8*)&plds[wid][l31][16 + hl * 8];
#pragma unroll
    for (int dblk = 0; dblk < 4; ++dblk) {
      const short* vrow = vbase + (dblk * 32 + l31) * 1024 + k0;
      short8 vb0 = *(const short8*)(vrow);
      short8 vb1 = *(const short8*)(vrow + 16);
      O[dblk] = MFMA32(ap0, vb0, O[dblk]);
      O[dblk] = MFMA32(ap1, vb1, O[dblk]);
    }
  }

  // reduce lsum over the 32 key-lanes (stays within hl group)
#pragma unroll
  for (int i = 0; i < 16; ++i) {
    float s = lsum[i];
    s += __shfl_xor(s, 1);  s += __shfl_xor(s, 2);
    s += __shfl_xor(s, 4);  s += __shfl_xor(s, 8);
    s += __shfl_xor(s, 16);
    lsum[i] = s;
  }

  if (wid == 1) {
#pragma unroll
    for (int i = 0; i < 16; ++i) {
      int qoff = (i & 3) + 8 * (i >> 2) + 4 * hl;
      if (l31 == 0) lbuf[qoff] = lsum[i];
#pragma unroll
      for (int dblk = 0; dblk < 4; ++dblk)
        obuf[qoff][dblk * 32 + l31] = O[dblk][i];
    }
  }
  __syncthreads();
  if (wid == 0) {
#pragma unroll
    for (int i = 0; i < 16; ++i) {
      int qoff = (i & 3) + 8 * (i >> 2) + 4 * hl;
      float inv = 1.f / (lsum[i] + lbuf[qoff]);
      short* orow = O2 + (b * 1024 + q0 + qoff) * 1024 + h;
#pragma unroll
      for (int dblk = 0; dblk < 4; ++dblk) {
        int d = dblk * 32 + l31;
        float v = O[dblk][i] + obuf[qoff][d];
        orow[d * 8] = f2bf(v * inv);
      }
    }
  }
}

extern "C" void kernel_launch(void* const* d_in, const int* in_sizes, int n_in,
                              void* d_out, int out_size, void* d_ws, size_t ws_size,
                              hipStream_t stream) {
  const float* Q   = (const float*)d_in[0];
  const float* K   = (const float*)d_in[1];
  const float* V   = (const float*)d_in[2];
  const unsigned char* kpm = (const unsigned char*)d_in[4];
  const float* Wq  = (const float*)d_in[5];
  const float* Wk  = (const float*)d_in[6];
  const float* Wv  = (const float*)d_in[7];
  const float* Wo  = (const float*)d_in[8];
  const float* rel = (const float*)d_in[9];
  float* out = (float*)d_out;

  short* ws = (short*)d_ws;
  short* Qb   = ws;
  short* Kb   = Qb + 4194304;
  short* Vb   = Kb + 4194304;
  short* Wqb  = Vb + 4194304;
  short* Wkb  = Wqb + 1048576;
  short* Wvb  = Wkb + 1048576;
  short* Wob  = Wvb + 1048576;
  short* relb = Wob + 1048576;
  short* Qp   = relb + 263168;
  short* Kp   = Qp + 4194304;
  short* Vt   = Kp + 4194304;
  short* Qrel = Vt + 4194304;
  short* O2   = Qrel + 8421376;

  Cvt8 ca;
  ca.in[0] = Q;  ca.out[0] = Qb;
  ca.in[1] = K;  ca.out[1] = Kb;
  ca.in[2] = V;  ca.out[2] = Vb;
  ca.in[3] = Wq; ca.out[3] = Wqb;
  ca.in[4] = Wk; ca.out[4] = Wkb;
  ca.in[5] = Wv; ca.out[5] = Wvb;
  ca.in[6] = Wo; ca.out[6] = Wob;
  ca.in[7] = rel; ca.out[7] = relb;
  cvt8_k<<<dim3(16641), dim3(256), 0, stream>>>(ca);

  gemm_qkv<<<dim3(768), dim3(256), 0, stream>>>(Qb, Kb, Vb, Wqb, Wkb, Wvb, Qp, Kp, Vt);
  qrel_k<<<dim3(8704), dim3(256), 0, stream>>>(Qp, relb, Qrel);
  attn_k<<<dim3(1024), dim3(128), 0, stream>>>(Qp, Kp, Vt, Qrel, kpm, O2);
  gemm_o<<<dim3(512), dim3(256), 0, stream>>>(O2, Wob, out);
}

// Round 6
// 278.945 us; speedup vs baseline: 1.1746x; 1.1746x over previous
//
#include <hip/hip_runtime.h>

typedef __attribute__((ext_vector_type(8))) short short8;
typedef __attribute__((ext_vector_type(4))) short short4v;
typedef __attribute__((ext_vector_type(4))) float float4a;
typedef __attribute__((ext_vector_type(16))) float float16a;

#define MFMA16(a, b, c) __builtin_amdgcn_mfma_f32_16x16x32_bf16(a, b, c, 0, 0, 0)
#define MFMA32(a, b, c) __builtin_amdgcn_mfma_f32_32x32x16_bf16(a, b, c, 0, 0, 0)

static __device__ __forceinline__ short f2bf(float f) {
  unsigned u = __builtin_bit_cast(unsigned, f);
  u += 0x7fff + ((u >> 16) & 1);   // RNE
  return (short)(u >> 16);
}
static __device__ __forceinline__ float bf2f(short s) {
  unsigned u = ((unsigned)(unsigned short)s) << 16;
  return __builtin_bit_cast(float, u);
}

// async global->LDS, 16 B per lane. LDS dest must be wave-uniform base + lane*16.
static __device__ __forceinline__ void gl2lds(const short* g, short* l) {
  __builtin_amdgcn_global_load_lds(
      (const __attribute__((address_space(1))) void*)g,
      (__attribute__((address_space(3))) void*)l,
      16, 0, 0);
}

// ---- fused f32->bf16 conversion for all 8 tensors ----
struct Cvt8 { const float* in[8]; short* out[8]; };
__global__ __launch_bounds__(256) void cvt8_k(Cvt8 a) {
  int b = blockIdx.x, seg, rb;
  if (b < 12288)      { seg = b >> 12;                 rb = b & 4095; }
  else if (b < 16384) { seg = 3 + ((b - 12288) >> 10); rb = (b - 12288) & 1023; }
  else                { seg = 7;                       rb = b - 16384; }
  int i = rb * 256 + threadIdx.x;
  float4a v = ((const float4a*)a.in[seg])[i];
  short4v o;
  o.x = f2bf(v.x); o.y = f2bf(v.y); o.z = f2bf(v.z); o.w = f2bf(v.w);
  ((short4v*)a.out[seg])[i] = o;
}

// ---- tiled GEMM: C = A @ W^T, 128x128 tile, BK=32. Fused Q/K/V projections. ----
__global__ __launch_bounds__(256) void gemm_qkv(
    const short* __restrict__ Qb, const short* __restrict__ Kb, const short* __restrict__ Vb,
    const short* __restrict__ Wq, const short* __restrict__ Wk, const short* __restrict__ Wv,
    short* __restrict__ Qp, short* __restrict__ Kp, short* __restrict__ Vt) {
  __shared__ short As[128 * 32];
  __shared__ short Bs[128 * 32];
  int seg = blockIdx.x >> 8, bid = blockIdx.x & 255;
  const short* A = seg == 0 ? Qb : (seg == 1 ? Kb : Vb);
  const short* W = seg == 0 ? Wq : (seg == 1 ? Wk : Wv);
  int mt = bid >> 3, nt = bid & 7;
  int m0 = mt * 128, n0 = nt * 128;
  int lane = threadIdx.x & 63, wid = threadIdx.x >> 6;
  int l15 = lane & 15, quad = lane >> 4;
  int wm = wid & 1, wn = wid >> 1;

  int lrow = lane >> 2, lcol = (lane & 3) * 8;
  const short* gA = A + (m0 + wid * 32 + lrow) * 1024 + lcol;
  const short* gB = W + (n0 + wid * 32 + lrow) * 1024 + lcol;
  short* lA = As + (wid * 32) * 32 + lane * 8;
  short* lB = Bs + (wid * 32) * 32 + lane * 8;

  float4a acc[4][4];
#pragma unroll
  for (int i = 0; i < 4; ++i)
#pragma unroll
    for (int j = 0; j < 4; ++j) acc[i][j] = (float4a){0, 0, 0, 0};

  for (int kc = 0; kc < 1024; kc += 32) {
    __syncthreads();
    gl2lds(gA + kc, lA);
    gl2lds(gA + 16 * 1024 + kc, lA + 16 * 32);
    gl2lds(gB + kc, lB);
    gl2lds(gB + 16 * 1024 + kc, lB + 16 * 32);
    __syncthreads();
    short8 af[4], bfr[4];
#pragma unroll
    for (int i = 0; i < 4; ++i)
      af[i] = *(const short8*)&As[(wm * 64 + i * 16 + l15) * 32 + quad * 8];
#pragma unroll
    for (int j = 0; j < 4; ++j)
      bfr[j] = *(const short8*)&Bs[(wn * 64 + j * 16 + l15) * 32 + quad * 8];
#pragma unroll
    for (int i = 0; i < 4; ++i)
#pragma unroll
      for (int j = 0; j < 4; ++j) acc[i][j] = MFMA16(af[i], bfr[j], acc[i][j]);
  }

#pragma unroll
  for (int i = 0; i < 4; ++i)
#pragma unroll
    for (int j = 0; j < 4; ++j)
#pragma unroll
      for (int r = 0; r < 4; ++r) {
        int m = m0 + wm * 64 + i * 16 + quad * 4 + r;
        int n = n0 + wn * 64 + j * 16 + l15;
        int bb = m >> 10, s = m & 1023, hh = n >> 7, d = n & 127;
        short v = f2bf(acc[i][j][r]);
        if (seg == 0)      Qp[(((bb * 8 + hh) * 1024) + s) * 128 + d] = v;
        else if (seg == 1) Kp[(((bb * 8 + hh) * 1024) + s) * 128 + d] = v;
        else               Vt[(bb * 8 + hh) * 131072 + d * 1024 + s] = v;
      }
}

// ---- output projection: out(f32) = O2 @ Wo^T. 128x64 tiles -> 512 blocks. ----
__global__ __launch_bounds__(256) void gemm_o(const short* __restrict__ A,
                                              const short* __restrict__ W,
                                              float* __restrict__ C) {
  __shared__ short As[128 * 32];
  __shared__ short Bs[64 * 32];
  int bid = blockIdx.x;
  int mt = bid >> 4, nt = bid & 15;
  int m0 = mt * 128, n0 = nt * 64;
  int lane = threadIdx.x & 63, wid = threadIdx.x >> 6;
  int l15 = lane & 15, quad = lane >> 4;
  int wm = wid & 1, wn = wid >> 1;

  int lrow = lane >> 2, lcol = (lane & 3) * 8;
  const short* gA = A + (m0 + wid * 32 + lrow) * 1024 + lcol;
  const short* gB = W + (n0 + wid * 16 + (lane >> 2)) * 1024 + lcol;
  short* lA = As + (wid * 32) * 32 + lane * 8;
  short* lB = Bs + (wid * 16) * 32 + lane * 8;

  float4a acc[4][2];
#pragma unroll
  for (int i = 0; i < 4; ++i)
#pragma unroll
    for (int j = 0; j < 2; ++j) acc[i][j] = (float4a){0, 0, 0, 0};

  for (int kc = 0; kc < 1024; kc += 32) {
    __syncthreads();
    gl2lds(gA + kc, lA);
    gl2lds(gA + 16 * 1024 + kc, lA + 16 * 32);
    gl2lds(gB + kc, lB);
    __syncthreads();
    short8 af[4], bfr[2];
#pragma unroll
    for (int i = 0; i < 4; ++i)
      af[i] = *(const short8*)&As[(wm * 64 + i * 16 + l15) * 32 + quad * 8];
#pragma unroll
    for (int j = 0; j < 2; ++j)
      bfr[j] = *(const short8*)&Bs[(wn * 32 + j * 16 + l15) * 32 + quad * 8];
#pragma unroll
    for (int i = 0; i < 4; ++i)
#pragma unroll
      for (int j = 0; j < 2; ++j) acc[i][j] = MFMA16(af[i], bfr[j], acc[i][j]);
  }

#pragma unroll
  for (int i = 0; i < 4; ++i)
#pragma unroll
    for (int j = 0; j < 2; ++j)
#pragma unroll
      for (int r = 0; r < 4; ++r) {
        int m = m0 + wm * 64 + i * 16 + quad * 4 + r;
        int n = n0 + wn * 32 + j * 16 + l15;
        C[m * 1024 + n] = acc[i][j][r];
      }
}

// Qrel[bh, q, r] = sum_d Qp[bh,q,d] * rel[h,r,d]   (bf16 out)
__global__ __launch_bounds__(256) void qrel_k(const short* __restrict__ Qp,
                                              const short* __restrict__ rel,
                                              short* __restrict__ Qrel) {
  int lane = threadIdx.x & 63, wid = threadIdx.x >> 6;
  int gw = blockIdx.x * 4 + wid;
  int bh = gw / 1088;
  int rem = gw - bh * 1088;
  int mt = rem / 17;
  int nt = rem - mt * 17;
  int l15 = lane & 15, quad = lane >> 4;
  int h = bh & 7;

  const short* arow = Qp + bh * 131072 + (mt * 16 + l15) * 128 + quad * 8;
  int col = nt * 16 + l15;
  int colc = col > 256 ? 256 : col;
  const short* brow = rel + (h * 257 + colc) * 128 + quad * 8;

  float4a acc = {0, 0, 0, 0};
#pragma unroll
  for (int kc = 0; kc < 128; kc += 32) {
    short8 a = *(const short8*)(arow + kc);
    short8 b = *(const short8*)(brow + kc);
    acc = MFMA16(a, b, acc);
  }
  if (col < 257) {
#pragma unroll
    for (int r = 0; r < 4; ++r) {
      int q = mt * 16 + quad * 4 + r;
      Qrel[bh * 263168 + q * 257 + col] = f2bf(acc[r]);
    }
  }
}

// Banded attention v3: no-max flash, 32x32x16 MFMA.
// Block = 64-query superblock, 4 waves = 2 q-tiles x 2 band-halves.
// Qrel rows staged in LDS; K-frag prefetch one chunk ahead; fp32 LDS combine.
__global__ __launch_bounds__(256, 2) void attn_k(const short* __restrict__ Qp,
                                                 const short* __restrict__ Kp,
                                                 const short* __restrict__ Vt,
                                                 const short* __restrict__ Qrel,
                                                 const unsigned char* __restrict__ kpm,
                                                 short* __restrict__ O2) {
  __shared__ short qlds[64 * 257];     // Qrel rows for the 64q superblock (33 KB)
  __shared__ short plds[4][32][40];    // per-wave P tile (10 KB)
  __shared__ float obuf[2][32][132];   // half-1 partial O, fp32 (33.8 KB)
  __shared__ float lbuf[2][32];
  int tid = threadIdx.x;
  int lane = tid & 63, wid = tid >> 6;
  int bh = blockIdx.x >> 4, qsb = blockIdx.x & 15;
  int q0b = qsb * 64;
  int qt = wid & 1, half = wid >> 1;
  int q0 = q0b + qt * 32;
  int l31 = lane & 31, hl = lane >> 5;
  int b = bh >> 3, h = bh & 7;

  // stage Qrel rows (64 x 257 shorts, 8B-aligned) into LDS
  {
    const unsigned long long* src =
        (const unsigned long long*)(Qrel + bh * 263168 + q0b * 257);
    unsigned long long* dst = (unsigned long long*)qlds;
    for (int i = tid; i < 4112; i += 256) dst[i] = src[i];
  }

  // Q A-fragments: lane holds Q[q0+l31][s*16 + hl*8 + j]
  short8 aq[8];
  const short* qrow = Qp + bh * 131072 + (q0 + l31) * 128 + hl * 8;
#pragma unroll
  for (int s = 0; s < 8; ++s) aq[s] = *(const short8*)(qrow + s * 16);
  __syncthreads();

  float16a O[4];
#pragma unroll
  for (int d = 0; d < 4; ++d)
#pragma unroll
    for (int i = 0; i < 16; ++i) O[d][i] = 0.f;
  float lsum[16];
#pragma unroll
  for (int i = 0; i < 16; ++i) lsum[i] = 0.f;

  int klo = q0 - 256; if (klo < 0) klo = 0; klo &= ~31;
  int khi = q0 + 288; if (khi > 1024) khi = 1024;
  const float sc = 0.08838834764831845f;  // 1/sqrt(128)

  const short* kbase = Kp + bh * 131072 + hl * 8;
  const short* vbase = Vt + bh * 131072 + hl * 8;
  const unsigned char* pmrow = kpm + b * 1024;
  const short* myq = qlds + (qt * 32) * 257;

  // prologue: K frags for first chunk of this half
  int k0 = klo + half * 32;
  short8 kb[8];
  {
    const short* krow = kbase + (k0 + l31) * 128;
#pragma unroll
    for (int s = 0; s < 8; ++s) kb[s] = *(const short8*)(krow + s * 16);
  }

  for (; k0 < khi; k0 += 64) {
    int key = k0 + l31;
    int pmv = pmrow[key];
    // S = Q K^T (uses current kb)
    float16a S;
#pragma unroll
    for (int i = 0; i < 16; ++i) S[i] = 0.f;
#pragma unroll
    for (int s = 0; s < 8; ++s) S = MFMA32(aq[s], kb[s], S);
    // prefetch next chunk's K frags (overlaps exp + PV below)
    int k1 = k0 + 64;
    if (k1 < khi) {
      const short* krow = kbase + (k1 + l31) * 128;
#pragma unroll
      for (int s = 0; s < 8; ++s) kb[s] = *(const short8*)(krow + s * 16);
    }
    // V loads for this chunk (issued before exp section)
    short8 vb0[4], vb1[4];
#pragma unroll
    for (int dblk = 0; dblk < 4; ++dblk) {
      const short* vrow = vbase + (dblk * 32 + l31) * 1024 + k0;
      vb0[dblk] = *(const short8*)(vrow);
      vb1[dblk] = *(const short8*)(vrow + 16);
    }
    // bias (from LDS) + exp + P store (C-layout row = (i&3)+8*(i>>2)+4*hl)
#pragma unroll
    for (int i = 0; i < 16; ++i) {
      int qoff = (i & 3) + 8 * (i >> 2) + 4 * hl;
      int q = q0 + qoff;
      int d = key - q;
      int rr = d < -128 ? 0 : (d > 128 ? 256 : d + 128);
      float rel = bf2f(myq[qoff * 257 + rr]);
      int msk = (d < -256) | (d > 256) | pmv;
      float pe = msk ? 0.f : __expf((S[i] + rel) * sc);
      lsum[i] += pe;
      plds[wid][qoff][l31] = f2bf(pe);
    }
    // P A-fragments (same wave's buffer; no barrier needed) and PV
    short8 ap0 = *(const short8*)&plds[wid][l31][hl * 8];
    short8 ap1 = *(const short8*)&plds[wid][l31][16 + hl * 8];
#pragma unroll
    for (int dblk = 0; dblk < 4; ++dblk) {
      O[dblk] = MFMA32(ap0, vb0[dblk], O[dblk]);
      O[dblk] = MFMA32(ap1, vb1[dblk], O[dblk]);
    }
  }

  // reduce lsum across the 32 key-lanes (bit5 untouched: stays within hl group)
#pragma unroll
  for (int i = 0; i < 16; ++i) {
    float s = lsum[i];
    s += __shfl_xor(s, 1);  s += __shfl_xor(s, 2);
    s += __shfl_xor(s, 4);  s += __shfl_xor(s, 8);
    s += __shfl_xor(s, 16);
    lsum[i] = s;
  }

  if (half == 1) {
#pragma unroll
    for (int i = 0; i < 16; ++i) {
      int qoff = (i & 3) + 8 * (i >> 2) + 4 * hl;
      if (l31 == 0) lbuf[qt][qoff] = lsum[i];
#pragma unroll
      for (int dblk = 0; dblk < 4; ++dblk)
        obuf[qt][qoff][dblk * 32 + l31] = O[dblk][i];
    }
  }
  __syncthreads();
  if (half == 0) {
#pragma unroll
    for (int i = 0; i < 16; ++i) {
      int qoff = (i & 3) + 8 * (i >> 2) + 4 * hl;
      float inv = 1.f / (lsum[i] + lbuf[qt][qoff]);
      short* orow = O2 + (b * 1024 + q0 + qoff) * 1024 + h;
#pragma unroll
      for (int dblk = 0; dblk < 4; ++dblk) {
        int d = dblk * 32 + l31;
        float v = O[dblk][i] + obuf[qt][qoff][d];
        orow[d * 8] = f2bf(v * inv);
      }
    }
  }
}

extern "C" void kernel_launch(void* const* d_in, const int* in_sizes, int n_in,
                              void* d_out, int out_size, void* d_ws, size_t ws_size,
                              hipStream_t stream) {
  const float* Q   = (const float*)d_in[0];
  const float* K   = (const float*)d_in[1];
  const float* V   = (const float*)d_in[2];
  const unsigned char* kpm = (const unsigned char*)d_in[4];
  const float* Wq  = (const float*)d_in[5];
  const float* Wk  = (const float*)d_in[6];
  const float* Wv  = (const float*)d_in[7];
  const float* Wo  = (const float*)d_in[8];
  const float* rel = (const float*)d_in[9];
  float* out = (float*)d_out;

  short* ws = (short*)d_ws;
  short* Qb   = ws;
  short* Kb   = Qb + 4194304;
  short* Vb   = Kb + 4194304;
  short* Wqb  = Vb + 4194304;
  short* Wkb  = Wqb + 1048576;
  short* Wvb  = Wkb + 1048576;
  short* Wob  = Wvb + 1048576;
  short* relb = Wob + 1048576;
  short* Qp   = relb + 263168;
  short* Kp   = Qp + 4194304;
  short* Vt   = Kp + 4194304;
  short* Qrel = Vt + 4194304;
  short* O2   = Qrel + 8421376;

  Cvt8 ca;
  ca.in[0] = Q;  ca.out[0] = Qb;
  ca.in[1] = K;  ca.out[1] = Kb;
  ca.in[2] = V;  ca.out[2] = Vb;
  ca.in[3] = Wq; ca.out[3] = Wqb;
  ca.in[4] = Wk; ca.out[4] = Wkb;
  ca.in[5] = Wv; ca.out[5] = Wvb;
  ca.in[6] = Wo; ca.out[6] = Wob;
  ca.in[7] = rel; ca.out[7] = relb;
  cvt8_k<<<dim3(16641), dim3(256), 0, stream>>>(ca);

  gemm_qkv<<<dim3(768), dim3(256), 0, stream>>>(Qb, Kb, Vb, Wqb, Wkb, Wvb, Qp, Kp, Vt);
  qrel_k<<<dim3(8704), dim3(256), 0, stream>>>(Qp, relb, Qrel);
  attn_k<<<dim3(512), dim3(256), 0, stream>>>(Qp, Kp, Vt, Qrel, kpm, O2);
  gemm_o<<<dim3(512), dim3(256), 0, stream>>>(O2, Wob, out);
}

// Round 7
// 255.402 us; speedup vs baseline: 1.2828x; 1.0922x over previous
//
#include <hip/hip_runtime.h>

typedef __attribute__((ext_vector_type(8))) short short8;
typedef __attribute__((ext_vector_type(4))) short short4v;
typedef __attribute__((ext_vector_type(4))) float float4a;
typedef __attribute__((ext_vector_type(16))) float float16a;

#define MFMA16(a, b, c) __builtin_amdgcn_mfma_f32_16x16x32_bf16(a, b, c, 0, 0, 0)
#define MFMA32(a, b, c) __builtin_amdgcn_mfma_f32_32x32x16_bf16(a, b, c, 0, 0, 0)

static __device__ __forceinline__ short f2bf(float f) {
  unsigned u = __builtin_bit_cast(unsigned, f);
  u += 0x7fff + ((u >> 16) & 1);   // RNE
  return (short)(u >> 16);
}
static __device__ __forceinline__ float bf2f(short s) {
  unsigned u = ((unsigned)(unsigned short)s) << 16;
  return __builtin_bit_cast(float, u);
}

// async global->LDS, 16 B per lane. LDS dest = wave-uniform base + lane*16.
static __device__ __forceinline__ void gl2lds(const short* g, short* l) {
  __builtin_amdgcn_global_load_lds(
      (const __attribute__((address_space(1))) void*)g,
      (__attribute__((address_space(3))) void*)l,
      16, 0, 0);
}

// ---- fused f32->bf16 conversion for all 8 tensors ----
struct Cvt8 { const float* in[8]; short* out[8]; };
__global__ __launch_bounds__(256) void cvt8_k(Cvt8 a) {
  int b = blockIdx.x, seg, rb;
  if (b < 12288)      { seg = b >> 12;                 rb = b & 4095; }
  else if (b < 16384) { seg = 3 + ((b - 12288) >> 10); rb = (b - 12288) & 1023; }
  else                { seg = 7;                       rb = b - 16384; }
  int i = rb * 256 + threadIdx.x;
  float4a v = ((const float4a*)a.in[seg])[i];
  short4v o;
  o.x = f2bf(v.x); o.y = f2bf(v.y); o.z = f2bf(v.z); o.w = f2bf(v.w);
  ((short4v*)a.out[seg])[i] = o;
}

// ---- tiled GEMM, BK=64 rows (128 B = all 32 banks) + XOR swizzle ----
// LDS slot (r, u) holds global 16B-unit u^(r&7); swizzle applied on the
// global source address since global_load_lds placement is lane-contiguous.
// Fused Q/K/V projections; 128x128 tile; 2x2 waves of 64x64.
__global__ __launch_bounds__(256) void gemm_qkv(
    const short* __restrict__ Qb, const short* __restrict__ Kb, const short* __restrict__ Vb,
    const short* __restrict__ Wq, const short* __restrict__ Wk, const short* __restrict__ Wv,
    short* __restrict__ Qp, short* __restrict__ Kp, short* __restrict__ Vt) {
  __shared__ short pool[16384];        // As=pool[0:8192), Bs=pool[8192:16384)
  short* As = pool;
  short* Bs = pool + 8192;
  int seg = blockIdx.x >> 8, bid = blockIdx.x & 255;
  const short* A = seg == 0 ? Qb : (seg == 1 ? Kb : Vb);
  const short* W = seg == 0 ? Wq : (seg == 1 ? Wk : Wv);
  int mt = bid >> 3, nt = bid & 7;
  int m0 = mt * 128, n0 = nt * 128;
  int tid = threadIdx.x;
  int lane = tid & 63, wid = tid >> 6;
  int l15 = lane & 15, quad = lane >> 4;
  int wm = wid & 1, wn = wid >> 1;

  // staging source: lane l covers row (l>>3), swizzled unit (l&7)^(l>>3)
  int srow = lane >> 3, sunit = (lane & 7) ^ (lane >> 3);
  const short* gA = A + (m0 + wid * 32 + srow) * 1024 + sunit * 8;
  const short* gB = W + (n0 + wid * 32 + srow) * 1024 + sunit * 8;
  short* lA = As + (wid * 32) * 64;
  short* lB = Bs + (wid * 32) * 64;
  int sw = l15 & 7;                    // fragment-read swizzle factor

  float4a acc[4][4];
#pragma unroll
  for (int i = 0; i < 4; ++i)
#pragma unroll
    for (int j = 0; j < 4; ++j) acc[i][j] = (float4a){0, 0, 0, 0};

  for (int kc = 0; kc < 1024; kc += 64) {
    __syncthreads();
#pragma unroll
    for (int t = 0; t < 4; ++t) {
      gl2lds(gA + kc + t * 8192, lA + t * 512);
      gl2lds(gB + kc + t * 8192, lB + t * 512);
    }
    __syncthreads();
#pragma unroll
    for (int ks = 0; ks < 2; ++ks) {
      short8 af[4], bfr[4];
#pragma unroll
      for (int i = 0; i < 4; ++i)
        af[i] = *(const short8*)&As[(wm * 64 + i * 16 + l15) * 64 +
                                    (((ks * 4 + quad) ^ sw) * 8)];
#pragma unroll
      for (int j = 0; j < 4; ++j)
        bfr[j] = *(const short8*)&Bs[(wn * 64 + j * 16 + l15) * 64 +
                                     (((ks * 4 + quad) ^ sw) * 8)];
#pragma unroll
      for (int i = 0; i < 4; ++i)
#pragma unroll
        for (int j = 0; j < 4; ++j) acc[i][j] = MFMA16(af[i], bfr[j], acc[i][j]);
    }
  }

  if (seg < 2) {
    // Qp/Kp: n = h*128+d, d consecutive across lanes -> direct stores
#pragma unroll
    for (int i = 0; i < 4; ++i)
#pragma unroll
      for (int j = 0; j < 4; ++j)
#pragma unroll
        for (int r = 0; r < 4; ++r) {
          int m = m0 + wm * 64 + i * 16 + quad * 4 + r;
          int n = n0 + wn * 64 + j * 16 + l15;
          int bb = m >> 10, s = m & 1023, hh = n >> 7, d = n & 127;
          short v = f2bf(acc[i][j][r]);
          if (seg == 0) Qp[(((bb * 8 + hh) * 1024) + s) * 128 + d] = v;
          else          Kp[(((bb * 8 + hh) * 1024) + s) * 128 + d] = v;
        }
  } else {
    // Vt: transpose through LDS, then coalesced 256B-row stores.
    // Block covers h = nt (full d range 0..127), b = m0>>10, s in [s0, s0+128)
    short* T = pool;                   // 64 x 132 shorts (16.5 KB < 32 KB pool)
    int b2 = m0 >> 10, s0 = m0 & 1023;
    long vb2 = (long)(b2 * 8 + nt) * 131072;
#pragma unroll
    for (int hd = 0; hd < 2; ++hd) {
      __syncthreads();
      if (wn == hd) {
#pragma unroll
        for (int j = 0; j < 4; ++j)
#pragma unroll
          for (int i = 0; i < 4; ++i)
#pragma unroll
            for (int r = 0; r < 4; ++r)
              T[(j * 16 + l15) * 132 + wm * 64 + i * 16 + quad * 4 + r] =
                  f2bf(acc[i][j][r]);
      }
      __syncthreads();
#pragma unroll
      for (int rr = 0; rr < 4; ++rr) {
        int d = rr * 16 + (tid >> 4);
        short8 v = *(const short8*)&T[d * 132 + (tid & 15) * 8];
        *(short8*)&Vt[vb2 + (hd * 64 + d) * 1024 + s0 + (tid & 15) * 8] = v;
      }
    }
  }
}

// ---- output projection: out(f32) = O2 @ Wo^T. 128x64 tiles, BK=64 swizzled. ----
__global__ __launch_bounds__(256) void gemm_o(const short* __restrict__ A,
                                              const short* __restrict__ W,
                                              float* __restrict__ C) {
  __shared__ short As[128 * 64];
  __shared__ short Bs[64 * 64];
  int bid = blockIdx.x;
  int mt = bid >> 4, nt = bid & 15;
  int m0 = mt * 128, n0 = nt * 64;
  int lane = threadIdx.x & 63, wid = threadIdx.x >> 6;
  int l15 = lane & 15, quad = lane >> 4;
  int wm = wid & 1, wn = wid >> 1;

  int srow = lane >> 3, sunit = (lane & 7) ^ (lane >> 3);
  const short* gA = A + (m0 + wid * 32 + srow) * 1024 + sunit * 8;
  const short* gB = W + (n0 + wid * 16 + srow) * 1024 + sunit * 8;
  short* lA = As + (wid * 32) * 64;
  short* lB = Bs + (wid * 16) * 64;
  int sw = l15 & 7;

  float4a acc[4][2];
#pragma unroll
  for (int i = 0; i < 4; ++i)
#pragma unroll
    for (int j = 0; j < 2; ++j) acc[i][j] = (float4a){0, 0, 0, 0};

  for (int kc = 0; kc < 1024; kc += 64) {
    __syncthreads();
#pragma unroll
    for (int t = 0; t < 4; ++t) gl2lds(gA + kc + t * 8192, lA + t * 512);
#pragma unroll
    for (int t = 0; t < 2; ++t) gl2lds(gB + kc + t * 8192, lB + t * 512);
    __syncthreads();
#pragma unroll
    for (int ks = 0; ks < 2; ++ks) {
      short8 af[4], bfr[2];
#pragma unroll
      for (int i = 0; i < 4; ++i)
        af[i] = *(const short8*)&As[(wm * 64 + i * 16 + l15) * 64 +
                                    (((ks * 4 + quad) ^ sw) * 8)];
#pragma unroll
      for (int j = 0; j < 2; ++j)
        bfr[j] = *(const short8*)&Bs[(wn * 32 + j * 16 + l15) * 64 +
                                     (((ks * 4 + quad) ^ sw) * 8)];
#pragma unroll
      for (int i = 0; i < 4; ++i)
#pragma unroll
        for (int j = 0; j < 2; ++j) acc[i][j] = MFMA16(af[i], bfr[j], acc[i][j]);
    }
  }

#pragma unroll
  for (int i = 0; i < 4; ++i)
#pragma unroll
    for (int j = 0; j < 2; ++j)
#pragma unroll
      for (int r = 0; r < 4; ++r) {
        int m = m0 + wm * 64 + i * 16 + quad * 4 + r;
        int n = n0 + wn * 32 + j * 16 + l15;
        C[m * 1024 + n] = acc[i][j][r];
      }
}

// Qrel[bh, q, r] = sum_d Qp[bh,q,d] * rel[h,r,d]   (bf16 out)
__global__ __launch_bounds__(256) void qrel_k(const short* __restrict__ Qp,
                                              const short* __restrict__ rel,
                                              short* __restrict__ Qrel) {
  int lane = threadIdx.x & 63, wid = threadIdx.x >> 6;
  int gw = blockIdx.x * 4 + wid;
  int bh = gw / 1088;
  int rem = gw - bh * 1088;
  int mt = rem / 17;
  int nt = rem - mt * 17;
  int l15 = lane & 15, quad = lane >> 4;
  int h = bh & 7;

  const short* arow = Qp + bh * 131072 + (mt * 16 + l15) * 128 + quad * 8;
  int col = nt * 16 + l15;
  int colc = col > 256 ? 256 : col;
  const short* brow = rel + (h * 257 + colc) * 128 + quad * 8;

  float4a acc = {0, 0, 0, 0};
#pragma unroll
  for (int kc = 0; kc < 128; kc += 32) {
    short8 a = *(const short8*)(arow + kc);
    short8 b = *(const short8*)(brow + kc);
    acc = MFMA16(a, b, acc);
  }
  if (col < 257) {
#pragma unroll
    for (int r = 0; r < 4; ++r) {
      int q = mt * 16 + quad * 4 + r;
      Qrel[bh * 263168 + q * 257 + col] = f2bf(acc[r]);
    }
  }
}

// Banded attention v3: no-max flash, 32x32x16 MFMA.
// Block = 64-query superblock, 4 waves = 2 q-tiles x 2 band-halves.
__global__ __launch_bounds__(256, 2) void attn_k(const short* __restrict__ Qp,
                                                 const short* __restrict__ Kp,
                                                 const short* __restrict__ Vt,
                                                 const short* __restrict__ Qrel,
                                                 const unsigned char* __restrict__ kpm,
                                                 short* __restrict__ O2) {
  __shared__ short qlds[64 * 257];
  __shared__ short plds[4][32][40];
  __shared__ float obuf[2][32][132];
  __shared__ float lbuf[2][32];
  int tid = threadIdx.x;
  int lane = tid & 63, wid = tid >> 6;
  int bh = blockIdx.x >> 4, qsb = blockIdx.x & 15;
  int q0b = qsb * 64;
  int qt = wid & 1, half = wid >> 1;
  int q0 = q0b + qt * 32;
  int l31 = lane & 31, hl = lane >> 5;
  int b = bh >> 3, h = bh & 7;

  {
    const unsigned long long* src =
        (const unsigned long long*)(Qrel + bh * 263168 + q0b * 257);
    unsigned long long* dst = (unsigned long long*)qlds;
    for (int i = tid; i < 4112; i += 256) dst[i] = src[i];
  }

  short8 aq[8];
  const short* qrow = Qp + bh * 131072 + (q0 + l31) * 128 + hl * 8;
#pragma unroll
  for (int s = 0; s < 8; ++s) aq[s] = *(const short8*)(qrow + s * 16);
  __syncthreads();

  float16a O[4];
#pragma unroll
  for (int d = 0; d < 4; ++d)
#pragma unroll
    for (int i = 0; i < 16; ++i) O[d][i] = 0.f;
  float lsum[16];
#pragma unroll
  for (int i = 0; i < 16; ++i) lsum[i] = 0.f;

  int klo = q0 - 256; if (klo < 0) klo = 0; klo &= ~31;
  int khi = q0 + 288; if (khi > 1024) khi = 1024;
  const float sc = 0.08838834764831845f;

  const short* kbase = Kp + bh * 131072 + hl * 8;
  const short* vbase = Vt + bh * 131072 + hl * 8;
  const unsigned char* pmrow = kpm + b * 1024;
  const short* myq = qlds + (qt * 32) * 257;

  int k0 = klo + half * 32;
  short8 kb[8];
  {
    const short* krow = kbase + (k0 + l31) * 128;
#pragma unroll
    for (int s = 0; s < 8; ++s) kb[s] = *(const short8*)(krow + s * 16);
  }

  for (; k0 < khi; k0 += 64) {
    int key = k0 + l31;
    int pmv = pmrow[key];
    float16a S;
#pragma unroll
    for (int i = 0; i < 16; ++i) S[i] = 0.f;
#pragma unroll
    for (int s = 0; s < 8; ++s) S = MFMA32(aq[s], kb[s], S);
    int k1 = k0 + 64;
    if (k1 < khi) {
      const short* krow = kbase + (k1 + l31) * 128;
#pragma unroll
      for (int s = 0; s < 8; ++s) kb[s] = *(const short8*)(krow + s * 16);
    }
    short8 vb0[4], vb1[4];
#pragma unroll
    for (int dblk = 0; dblk < 4; ++dblk) {
      const short* vrow = vbase + (dblk * 32 + l31) * 1024 + k0;
      vb0[dblk] = *(const short8*)(vrow);
      vb1[dblk] = *(const short8*)(vrow + 16);
    }
#pragma unroll
    for (int i = 0; i < 16; ++i) {
      int qoff = (i & 3) + 8 * (i >> 2) + 4 * hl;
      int q = q0 + qoff;
      int d = key - q;
      int rr = d < -128 ? 0 : (d > 128 ? 256 : d + 128);
      float rel = bf2f(myq[qoff * 257 + rr]);
      int msk = (d < -256) | (d > 256) | pmv;
      float pe = msk ? 0.f : __expf((S[i] + rel) * sc);
      lsum[i] += pe;
      plds[wid][qoff][l31] = f2bf(pe);
    }
    short8 ap0 = *(const short8*)&plds[wid][l31][hl * 8];
    short8 ap1 = *(const short8*)&plds[wid][l31][16 + hl * 8];
#pragma unroll
    for (int dblk = 0; dblk < 4; ++dblk) {
      O[dblk] = MFMA32(ap0, vb0[dblk], O[dblk]);
      O[dblk] = MFMA32(ap1, vb1[dblk], O[dblk]);
    }
  }

#pragma unroll
  for (int i = 0; i < 16; ++i) {
    float s = lsum[i];
    s += __shfl_xor(s, 1);  s += __shfl_xor(s, 2);
    s += __shfl_xor(s, 4);  s += __shfl_xor(s, 8);
    s += __shfl_xor(s, 16);
    lsum[i] = s;
  }

  if (half == 1) {
#pragma unroll
    for (int i = 0; i < 16; ++i) {
      int qoff = (i & 3) + 8 * (i >> 2) + 4 * hl;
      if (l31 == 0) lbuf[qt][qoff] = lsum[i];
#pragma unroll
      for (int dblk = 0; dblk < 4; ++dblk)
        obuf[qt][qoff][dblk * 32 + l31] = O[dblk][i];
    }
  }
  __syncthreads();
  if (half == 0) {
#pragma unroll
    for (int i = 0; i < 16; ++i) {
      int qoff = (i & 3) + 8 * (i >> 2) + 4 * hl;
      float inv = 1.f / (lsum[i] + lbuf[qt][qoff]);
      short* orow = O2 + (b * 1024 + q0 + qoff) * 1024 + h;
#pragma unroll
      for (int dblk = 0; dblk < 4; ++dblk) {
        int d = dblk * 32 + l31;
        float v = O[dblk][i] + obuf[qt][qoff][d];
        orow[d * 8] = f2bf(v * inv);
      }
    }
  }
}

extern "C" void kernel_launch(void* const* d_in, const int* in_sizes, int n_in,
                              void* d_out, int out_size, void* d_ws, size_t ws_size,
                              hipStream_t stream) {
  const float* Q   = (const float*)d_in[0];
  const float* K   = (const float*)d_in[1];
  const float* V   = (const float*)d_in[2];
  const unsigned char* kpm = (const unsigned char*)d_in[4];
  const float* Wq  = (const float*)d_in[5];
  const float* Wk  = (const float*)d_in[6];
  const float* Wv  = (const float*)d_in[7];
  const float* Wo  = (const float*)d_in[8];
  const float* rel = (const float*)d_in[9];
  float* out = (float*)d_out;

  short* ws = (short*)d_ws;
  short* Qb   = ws;
  short* Kb   = Qb + 4194304;
  short* Vb   = Kb + 4194304;
  short* Wqb  = Vb + 4194304;
  short* Wkb  = Wqb + 1048576;
  short* Wvb  = Wkb + 1048576;
  short* Wob  = Wvb + 1048576;
  short* relb = Wob + 1048576;
  short* Qp   = relb + 263168;
  short* Kp   = Qp + 4194304;
  short* Vt   = Kp + 4194304;
  short* Qrel = Vt + 4194304;
  short* O2   = Qrel + 8421376;

  Cvt8 ca;
  ca.in[0] = Q;  ca.out[0] = Qb;
  ca.in[1] = K;  ca.out[1] = Kb;
  ca.in[2] = V;  ca.out[2] = Vb;
  ca.in[3] = Wq; ca.out[3] = Wqb;
  ca.in[4] = Wk; ca.out[4] = Wkb;
  ca.in[5] = Wv; ca.out[5] = Wvb;
  ca.in[6] = Wo; ca.out[6] = Wob;
  ca.in[7] = rel; ca.out[7] = relb;
  cvt8_k<<<dim3(16641), dim3(256), 0, stream>>>(ca);

  gemm_qkv<<<dim3(768), dim3(256), 0, stream>>>(Qb, Kb, Vb, Wqb, Wkb, Wvb, Qp, Kp, Vt);
  qrel_k<<<dim3(8704), dim3(256), 0, stream>>>(Qp, relb, Qrel);
  attn_k<<<dim3(512), dim3(256), 0, stream>>>(Qp, Kp, Vt, Qrel, kpm, O2);
  gemm_o<<<dim3(512), dim3(256), 0, stream>>>(O2, Wob, out);
}